// Round 2
// baseline (1011.560 us; speedup 1.0000x reference)
//
#include <hip/hip_runtime.h>
#include <hip/hip_bf16.h>
#include <math.h>

#define B_   2
#define S_   2048
#define H_   32
#define HKV_ 8
#define HD_  64
#define D_   2048
#define DKV_ 512
#define M_   (B_*S_)

typedef __attribute__((ext_vector_type(8))) short bf16x8;
typedef __attribute__((ext_vector_type(4))) float f32x4;
typedef unsigned short u16;

__device__ __forceinline__ u16 f2bf(float f) {
    union { float f; unsigned u; } v; v.f = f;
    unsigned r = v.u + 0x7fff + ((v.u >> 16) & 1);
    return (u16)(r >> 16);
}
__device__ __forceinline__ float bf2f(u16 h) {
    union { unsigned u; float f; } v; v.u = ((unsigned)h) << 16;
    return v.f;
}

// ---------------- RoPE table: cos/sin(s * 2*pi * theta^(-i/32)) ----------------
__global__ void rope_table_kernel(float* __restrict__ tab) {
    int idx = blockIdx.x * blockDim.x + threadIdx.x;   // 65536 entries
    int s = idx >> 5, i = idx & 31;
    double freq = pow(10000.0, -(double)i / 32.0);
    double ang = (double)s * 6.283185307179586476925286766559 * freq;
    tab[2*idx]   = (float)cos(ang);
    tab[2*idx+1] = (float)sin(ang);
}

// ---------------- In-place RoPE on (M, nh*64) bf16 buffer ----------------
__global__ void rope_apply_kernel(u16* __restrict__ buf, const float* __restrict__ tab, int nh) {
    int p = blockIdx.x * blockDim.x + threadIdx.x;
    int cols = nh * 32;                 // pairs per row
    int i = p & 31;                     // cols is a multiple of 32
    int row = p / cols;
    int col = p - row * cols;           // = h*32 + i
    int s = row & (S_ - 1);
    float c  = tab[(s*32 + i)*2 + 0];
    float sn = tab[(s*32 + i)*2 + 1];
    u16* ptr = buf + (size_t)row * (nh*64) + col*2;
    float x0 = bf2f(ptr[0]), x1 = bf2f(ptr[1]);
    ptr[0] = f2bf(x0*c - x1*sn);
    ptr[1] = f2bf(x0*sn + x1*c);
}

// ---------------- GEMM: Y[M,N] = X[M,K] @ W[N,K]^T  (bf16 MFMA, fp32 accum) ----
// XF32/WF32: input dtype is float32 (convert to bf16 while staging into LDS).
// YF32: write float32 output, else bf16.
#define BM 128
#define BN 128
#define BK 32
#define LDK 40   // padded LDS stride (bf16 elems); 80B rows -> conflict-free b128 reads

// stage 8 contiguous elements (16B of bf16) into LDS, converting if f32
template<bool F32>
__device__ __forceinline__ void stage8(const void* src, u16* dst, size_t row, int col, int ld) {
    if constexpr (F32) {
        const float* p = (const float*)src + row * (size_t)ld + col;
        float4 a = *(const float4*)p;
        float4 b = *(const float4*)(p + 4);
        u16 tmp[8] = {f2bf(a.x), f2bf(a.y), f2bf(a.z), f2bf(a.w),
                      f2bf(b.x), f2bf(b.y), f2bf(b.z), f2bf(b.w)};
        *(uint4*)dst = *(const uint4*)tmp;
    } else {
        const u16* p = (const u16*)src + row * (size_t)ld + col;
        *(uint4*)dst = *(const uint4*)p;
    }
}

template<bool XF32, bool WF32, bool YF32>
__launch_bounds__(256, 2)
__global__ void gemm_bt(const void* __restrict__ X, const void* __restrict__ W,
                        void* __restrict__ Y, int Mdim, int Ndim, int Kdim) {
    __shared__ u16 As[BM*LDK];
    __shared__ u16 Bs[BN*LDK];
    int tid = threadIdx.x;
    int wv = tid >> 6, lane = tid & 63;
    int quad = lane >> 4, lr = lane & 15;
    int wm = wv >> 1, wn = wv & 1;
    int m0 = blockIdx.y * BM, n0 = blockIdx.x * BN;

    f32x4 acc[4][4] = {};
    for (int k0 = 0; k0 < Kdim; k0 += BK) {
        __syncthreads();
        #pragma unroll
        for (int it = 0; it < 2; ++it) {
            int e = (it*256 + tid) * 8;
            int r = e >> 5, kk = e & 31;
            stage8<XF32>(X, &As[r*LDK + kk], (size_t)(m0 + r), k0 + kk, Kdim);
            stage8<WF32>(W, &Bs[r*LDK + kk], (size_t)(n0 + r), k0 + kk, Kdim);
        }
        __syncthreads();
        bf16x8 af[4], bfr[4];
        #pragma unroll
        for (int t = 0; t < 4; ++t) {
            af[t]  = *(const bf16x8*)(&As[(wm*64 + t*16 + lr)*LDK + quad*8]);
            bfr[t] = *(const bf16x8*)(&Bs[(wn*64 + t*16 + lr)*LDK + quad*8]);
        }
        #pragma unroll
        for (int mt = 0; mt < 4; ++mt)
            #pragma unroll
            for (int nt = 0; nt < 4; ++nt)
                acc[mt][nt] = __builtin_amdgcn_mfma_f32_16x16x32_bf16(af[mt], bfr[nt], acc[mt][nt], 0, 0, 0);
    }
    #pragma unroll
    for (int mt = 0; mt < 4; ++mt)
        #pragma unroll
        for (int nt = 0; nt < 4; ++nt)
            #pragma unroll
            for (int r = 0; r < 4; ++r) {
                int m = m0 + wm*64 + mt*16 + quad*4 + r;
                int n = n0 + wn*64 + nt*16 + lr;
                if constexpr (YF32)
                    ((float*)Y)[(size_t)m*Ndim + n] = acc[mt][nt][r];
                else
                    ((u16*)Y)[(size_t)m*Ndim + n] = f2bf(acc[mt][nt][r]);
            }
}

// ---------------- Flash attention: per (b,h,q-tile of 64) ----------------
#define LVD 68   // V tile LDS stride
#define LP  72   // P tile LDS stride

__launch_bounds__(256, 2)
__global__ void attn_kernel(const u16* __restrict__ q, const u16* __restrict__ k,
                            const u16* __restrict__ v, u16* __restrict__ z) {
    __shared__ u16 Vs[64*LVD];
    __shared__ u16 Ps[4*16*LP];
    int tid = threadIdx.x;
    int wv = tid >> 6, lane = tid & 63;
    int quad = lane >> 4, lr = lane & 15;
    int b = blockIdx.z, h = blockIdx.y, qt = blockIdx.x;
    int kvh = h >> 2;
    int q0 = qt * 64;
    int qrow_base = q0 + wv*16;

    bf16x8 aq[2];
    {
        const u16* qp = q + ((size_t)(b*S_ + qrow_base + lr) * D_ + h*HD_ + quad*8);
        aq[0] = *(const bf16x8*)(qp);
        aq[1] = *(const bf16x8*)(qp + 32);
    }

    float mrow[4], lsum[4];
    #pragma unroll
    for (int r = 0; r < 4; ++r) { mrow[r] = -INFINITY; lsum[r] = 0.f; }
    f32x4 oacc[4] = {};

    for (int j = 0; j <= qt; ++j) {
        int kv0 = j * 64;
        __syncthreads();
        #pragma unroll
        for (int it = 0; it < 4; ++it) {
            int e = (it*256 + tid) * 4;
            int r = e >> 6, d = e & 63;
            uint2 vvv = *(const uint2*)(v + ((size_t)(b*S_ + kv0 + r) * DKV_ + kvh*HD_ + d));
            *(uint2*)(&Vs[r*LVD + d]) = vvv;
        }
        __syncthreads();

        // S = Q K^T
        f32x4 sacc[4] = {};
        #pragma unroll
        for (int nt = 0; nt < 4; ++nt) {
            const u16* kp = k + ((size_t)(b*S_ + kv0 + nt*16 + lr) * DKV_ + kvh*HD_ + quad*8);
            bf16x8 bk0 = *(const bf16x8*)(kp);
            bf16x8 bk1 = *(const bf16x8*)(kp + 32);
            sacc[nt] = __builtin_amdgcn_mfma_f32_16x16x32_bf16(aq[0], bk0, sacc[nt], 0, 0, 0);
            sacc[nt] = __builtin_amdgcn_mfma_f32_16x16x32_bf16(aq[1], bk1, sacc[nt], 0, 0, 0);
        }

        // mask + scale + online softmax (row = quad*4+r, cols across 16 lanes of quad)
        float pmat[4][4];
        #pragma unroll
        for (int r = 0; r < 4; ++r) {
            int qg = qrow_base + quad*4 + r;
            float mx = -INFINITY;
            #pragma unroll
            for (int nt = 0; nt < 4; ++nt) {
                int kg = kv0 + nt*16 + lr;
                float sc = sacc[nt][r] * 0.125f;
                if (kg > qg) sc = -INFINITY;
                pmat[nt][r] = sc;
                mx = fmaxf(mx, sc);
            }
            #pragma unroll
            for (int off = 8; off >= 1; off >>= 1)
                mx = fmaxf(mx, __shfl_xor(mx, off, 16));
            float mnew = fmaxf(mrow[r], mx);
            float alpha = (mnew == -INFINITY) ? 1.0f : expf(mrow[r] - mnew);
            float rsum = 0.f;
            #pragma unroll
            for (int nt = 0; nt < 4; ++nt) {
                float p = (pmat[nt][r] == -INFINITY) ? 0.f : expf(pmat[nt][r] - mnew);
                pmat[nt][r] = p;
                rsum += p;
            }
            #pragma unroll
            for (int off = 8; off >= 1; off >>= 1)
                rsum += __shfl_xor(rsum, off, 16);
            lsum[r] = lsum[r] * alpha + rsum;
            mrow[r] = mnew;
            #pragma unroll
            for (int nt = 0; nt < 4; ++nt)
                oacc[nt][r] *= alpha;
        }

        // P: C-layout -> A-layout via per-wave LDS (same wave, DS ops in order)
        u16* pw = &Ps[wv*16*LP];
        #pragma unroll
        for (int r = 0; r < 4; ++r)
            #pragma unroll
            for (int nt = 0; nt < 4; ++nt)
                pw[(quad*4 + r)*LP + nt*16 + lr] = f2bf(pmat[nt][r]);
        bf16x8 ap[2];
        ap[0] = *(const bf16x8*)(&pw[lr*LP + quad*8]);
        ap[1] = *(const bf16x8*)(&pw[lr*LP + 32 + quad*8]);

        // O += P V
        #pragma unroll
        for (int nt = 0; nt < 4; ++nt)
            #pragma unroll
            for (int ks = 0; ks < 2; ++ks) {
                bf16x8 bv;
                #pragma unroll
                for (int jj = 0; jj < 8; ++jj)
                    bv[jj] = (short)Vs[(ks*32 + quad*8 + jj)*LVD + nt*16 + lr];
                oacc[nt] = __builtin_amdgcn_mfma_f32_16x16x32_bf16(ap[ks], bv, oacc[nt], 0, 0, 0);
            }
    }

    #pragma unroll
    for (int nt = 0; nt < 4; ++nt)
        #pragma unroll
        for (int r = 0; r < 4; ++r) {
            int srow = qrow_base + quad*4 + r;
            float val = oacc[nt][r] / lsum[r];
            z[(size_t)(b*S_ + srow) * D_ + h*HD_ + nt*16 + lr] = f2bf(val);
        }
}

extern "C" void kernel_launch(void* const* d_in, const int* in_sizes, int n_in,
                              void* d_out, int out_size, void* d_ws, size_t ws_size,
                              hipStream_t stream) {
    // Reference dtypes: all inputs float32, output float32.
    const float* x  = (const float*)d_in[0];
    const float* Wq = (const float*)d_in[1];
    const float* Wk = (const float*)d_in[2];
    const float* Wv = (const float*)d_in[3];
    const float* Wo = (const float*)d_in[4];
    float* out = (float*)d_out;

    char* ws = (char*)d_ws;
    float* tab = (float*)ws;                                   // 512 KB
    u16* qbuf = (u16*)(ws + (size_t)524288);                   // 16 MB
    u16* kbuf = (u16*)(ws + (size_t)524288 + 16777216);        // 4 MB
    u16* vbuf = (u16*)(ws + (size_t)524288 + 20971520);        // 4 MB
    u16* zbuf = (u16*)(ws + (size_t)524288 + 25165824);        // 16 MB

    rope_table_kernel<<<256, 256, 0, stream>>>(tab);
    gemm_bt<true, true, false><<<dim3(D_/BN,   M_/BM), 256, 0, stream>>>(x, Wq, qbuf, M_, D_,   D_);
    gemm_bt<true, true, false><<<dim3(DKV_/BN, M_/BM), 256, 0, stream>>>(x, Wk, kbuf, M_, DKV_, D_);
    gemm_bt<true, true, false><<<dim3(DKV_/BN, M_/BM), 256, 0, stream>>>(x, Wv, vbuf, M_, DKV_, D_);
    rope_apply_kernel<<<(M_*H_*32)/256,   256, 0, stream>>>(qbuf, tab, H_);
    rope_apply_kernel<<<(M_*HKV_*32)/256, 256, 0, stream>>>(kbuf, tab, HKV_);
    attn_kernel<<<dim3(S_/64, H_, B_), 256, 0, stream>>>(qbuf, kbuf, vbuf, zbuf);
    gemm_bt<false, true, true><<<dim3(D_/BN, M_/BM), 256, 0, stream>>>(zbuf, Wo, out, M_, D_, D_);
}

// Round 3
// 563.482 us; speedup vs baseline: 1.7952x; 1.7952x over previous
//
#include <hip/hip_runtime.h>
#include <hip/hip_bf16.h>
#include <math.h>

#define B_   2
#define S_   2048
#define H_   32
#define HKV_ 8
#define HD_  64
#define D_   2048
#define DKV_ 512
#define M_   (B_*S_)

typedef __attribute__((ext_vector_type(8))) short bf16x8;
typedef __attribute__((ext_vector_type(4))) float f32x4;
typedef unsigned short u16;

__device__ __forceinline__ u16 f2bf(float f) {
    union { float f; unsigned u; } v; v.f = f;
    unsigned r = v.u + 0x7fff + ((v.u >> 16) & 1);
    return (u16)(r >> 16);
}
__device__ __forceinline__ float bf2f(u16 h) {
    union { unsigned u; float f; } v; v.u = ((unsigned)h) << 16;
    return v.f;
}

// async global->LDS, 16B per lane; LDS dest = uniform base + lane*16
typedef __attribute__((address_space(3))) void lds_void;
typedef const __attribute__((address_space(1))) void g_void;
__device__ __forceinline__ void gl_lds16(const void* g, void* l) {
    __builtin_amdgcn_global_load_lds((g_void*)g, (lds_void*)l, 16, 0, 0);
}

// ---------------- f32 -> bf16 bulk convert (8 elems/thread) ----------------
__global__ void cvt_bf16_kernel(const float* __restrict__ src, u16* __restrict__ dst, int n8) {
    int i = blockIdx.x * blockDim.x + threadIdx.x;
    if (i >= n8) return;
    const float4* p = (const float4*)(src + (size_t)i * 8);
    float4 a = p[0], b = p[1];
    u16 tmp[8] = {f2bf(a.x), f2bf(a.y), f2bf(a.z), f2bf(a.w),
                  f2bf(b.x), f2bf(b.y), f2bf(b.z), f2bf(b.w)};
    *(uint4*)(dst + (size_t)i * 8) = *(const uint4*)tmp;
}

// ---------------- RoPE table: cos/sin(s * 2*pi * theta^(-i/32)) ----------------
__global__ void rope_table_kernel(float* __restrict__ tab) {
    int idx = blockIdx.x * blockDim.x + threadIdx.x;   // 65536 entries
    int s = idx >> 5, i = idx & 31;
    double freq = pow(10000.0, -(double)i / 32.0);
    double ang = (double)s * 6.283185307179586476925286766559 * freq;
    tab[2*idx]   = (float)cos(ang);
    tab[2*idx+1] = (float)sin(ang);
}

// ---------------- In-place RoPE on (M, nh*64) bf16 buffer ----------------
__global__ void rope_apply_kernel(u16* __restrict__ buf, const float* __restrict__ tab, int nh) {
    int p = blockIdx.x * blockDim.x + threadIdx.x;
    int cols = nh * 32;
    int i = p & 31;
    int row = p / cols;
    int col = p - row * cols;
    int s = row & (S_ - 1);
    float c  = tab[(s*32 + i)*2 + 0];
    float sn = tab[(s*32 + i)*2 + 1];
    u16* ptr = buf + (size_t)row * (nh*64) + col*2;
    float x0 = bf2f(ptr[0]), x1 = bf2f(ptr[1]);
    ptr[0] = f2bf(x0*c - x1*sn);
    ptr[1] = f2bf(x0*sn + x1*c);
}

// ============ fast GEMM (m97 structure): Y[M,N] = X[M,K] @ W[N,K]^T, bf16 in ============
template<bool YF32>
__launch_bounds__(256, 2)
__global__ void gemm_bt_bf16(const u16* __restrict__ X, const u16* __restrict__ W,
                             void* __restrict__ Y, int Ndim, int Kdim) {
    __shared__ u16 As[128*32];   // unpadded: global_load_lds needs lane-contiguous layout
    __shared__ u16 Bs[128*32];
    int tid = threadIdx.x;
    int wv = tid >> 6, lane = tid & 63;
    int quad = lane >> 4, lr = lane & 15;
    int wm = wv >> 1, wn = wv & 1;
    int m0 = blockIdx.y * 128, n0 = blockIdx.x * 128;

    // staging: wave wv chunk c covers rows wv*32+c*16 + lane/4, cols (lane&3)*8
    int srow = wv*32 + (lane >> 2);
    int scol = (lane & 3) * 8;
    const u16* xp = X + (size_t)(m0 + srow)*Kdim + scol;
    const u16* wp = W + (size_t)(n0 + srow)*Kdim + scol;

    f32x4 acc[4][4] = {};
    for (int k0 = 0; k0 < Kdim; k0 += 32) {
        __syncthreads();
        gl_lds16(xp + k0,               &As[wv*1024]);
        gl_lds16(xp + 16*(size_t)Kdim + k0, &As[wv*1024 + 512]);
        gl_lds16(wp + k0,               &Bs[wv*1024]);
        gl_lds16(wp + 16*(size_t)Kdim + k0, &Bs[wv*1024 + 512]);
        __syncthreads();
        bf16x8 af[4], bfr[4];
        #pragma unroll
        for (int t = 0; t < 4; ++t) {
            af[t]  = *(const bf16x8*)(&As[(wm*64 + t*16 + lr)*32 + quad*8]);
            bfr[t] = *(const bf16x8*)(&Bs[(wn*64 + t*16 + lr)*32 + quad*8]);
        }
        #pragma unroll
        for (int mt = 0; mt < 4; ++mt)
            #pragma unroll
            for (int nt = 0; nt < 4; ++nt)
                acc[mt][nt] = __builtin_amdgcn_mfma_f32_16x16x32_bf16(af[mt], bfr[nt], acc[mt][nt], 0, 0, 0);
    }
    #pragma unroll
    for (int mt = 0; mt < 4; ++mt)
        #pragma unroll
        for (int nt = 0; nt < 4; ++nt)
            #pragma unroll
            for (int r = 0; r < 4; ++r) {
                int m = m0 + wm*64 + mt*16 + quad*4 + r;
                int n = n0 + wn*64 + nt*16 + lr;
                if constexpr (YF32)
                    ((float*)Y)[(size_t)m*Ndim + n] = acc[mt][nt][r];
                else
                    ((u16*)Y)[(size_t)m*Ndim + n] = f2bf(acc[mt][nt][r]);
            }
}

// ============ fallback GEMM (round-2): f32 inputs converted during staging ============
#define LDK 40
template<bool F32>
__device__ __forceinline__ void stage8(const void* src, u16* dst, size_t row, int col, int ld) {
    if constexpr (F32) {
        const float* p = (const float*)src + row * (size_t)ld + col;
        float4 a = *(const float4*)p;
        float4 b = *(const float4*)(p + 4);
        u16 tmp[8] = {f2bf(a.x), f2bf(a.y), f2bf(a.z), f2bf(a.w),
                      f2bf(b.x), f2bf(b.y), f2bf(b.z), f2bf(b.w)};
        *(uint4*)dst = *(const uint4*)tmp;
    } else {
        const u16* p = (const u16*)src + row * (size_t)ld + col;
        *(uint4*)dst = *(const uint4*)p;
    }
}

template<bool XF32, bool WF32, bool YF32>
__launch_bounds__(256, 2)
__global__ void gemm_bt(const void* __restrict__ X, const void* __restrict__ W,
                        void* __restrict__ Y, int Mdim, int Ndim, int Kdim) {
    __shared__ u16 As[128*LDK];
    __shared__ u16 Bs[128*LDK];
    int tid = threadIdx.x;
    int wv = tid >> 6, lane = tid & 63;
    int quad = lane >> 4, lr = lane & 15;
    int wm = wv >> 1, wn = wv & 1;
    int m0 = blockIdx.y * 128, n0 = blockIdx.x * 128;

    f32x4 acc[4][4] = {};
    for (int k0 = 0; k0 < Kdim; k0 += 32) {
        __syncthreads();
        #pragma unroll
        for (int it = 0; it < 2; ++it) {
            int e = (it*256 + tid) * 8;
            int r = e >> 5, kk = e & 31;
            stage8<XF32>(X, &As[r*LDK + kk], (size_t)(m0 + r), k0 + kk, Kdim);
            stage8<WF32>(W, &Bs[r*LDK + kk], (size_t)(n0 + r), k0 + kk, Kdim);
        }
        __syncthreads();
        bf16x8 af[4], bfr[4];
        #pragma unroll
        for (int t = 0; t < 4; ++t) {
            af[t]  = *(const bf16x8*)(&As[(wm*64 + t*16 + lr)*LDK + quad*8]);
            bfr[t] = *(const bf16x8*)(&Bs[(wn*64 + t*16 + lr)*LDK + quad*8]);
        }
        #pragma unroll
        for (int mt = 0; mt < 4; ++mt)
            #pragma unroll
            for (int nt = 0; nt < 4; ++nt)
                acc[mt][nt] = __builtin_amdgcn_mfma_f32_16x16x32_bf16(af[mt], bfr[nt], acc[mt][nt], 0, 0, 0);
    }
    #pragma unroll
    for (int mt = 0; mt < 4; ++mt)
        #pragma unroll
        for (int nt = 0; nt < 4; ++nt)
            #pragma unroll
            for (int r = 0; r < 4; ++r) {
                int m = m0 + wm*64 + mt*16 + quad*4 + r;
                int n = n0 + wn*64 + nt*16 + lr;
                if constexpr (YF32)
                    ((float*)Y)[(size_t)m*Ndim + n] = acc[mt][nt][r];
                else
                    ((u16*)Y)[(size_t)m*Ndim + n] = f2bf(acc[mt][nt][r]);
            }
}

// ---------------- Flash attention v2 ----------------
// - V staged transposed + XOR-swizzled: el(d,kv) at Vt[d*64 + (kv ^ (8*((d>>3)&7)))]
//   -> transpose writes are 2-way (free), fragment reads are single ds_read_b128.
// - fixed-offset softmax: p = exp2(s*0.125*log2e - 4); row sums via ones-MFMA.
// - qt reversed so longest blocks dispatch first (load balance).
#define LP 72   // P tile LDS stride (u16); 144B rows keep b128 aligned

__launch_bounds__(256, 2)
__global__ void attn_kernel(const u16* __restrict__ q, const u16* __restrict__ k,
                            const u16* __restrict__ v, u16* __restrict__ z) {
    __shared__ u16 Vt[64*64];
    __shared__ u16 Ps[4*16*LP];
    int tid = threadIdx.x;
    int wv = tid >> 6, lane = tid & 63;
    int quad = lane >> 4, lr = lane & 15;
    int b = blockIdx.z, h = blockIdx.y;
    int qt = (gridDim.x - 1) - blockIdx.x;
    int kvh = h >> 2;
    int q0 = qt * 64;
    int qrow_base = q0 + wv*16;

    // V staging ids: col group sg (8 d's), row-pair sp (kv = 2sp, 2sp+1)
    int sg = tid & 7;
    int sp = tid >> 3;
    const u16* vbase = v + ((size_t)(b*S_) * DKV_ + kvh*HD_);

    bf16x8 aq[2];
    {
        const u16* qp = q + ((size_t)(b*S_ + qrow_base + lr) * D_ + h*HD_ + quad*8);
        aq[0] = *(const bf16x8*)(qp);
        aq[1] = *(const bf16x8*)(qp + 32);
    }
    bf16x8 ones;
    #pragma unroll
    for (int i = 0; i < 8; ++i) ones[i] = (short)0x3F80;

    f32x4 oacc[4] = {};
    f32x4 lacc = {};
    const float SC = 0.18033688f;   // 0.125 * log2(e)

    for (int j = 0; j <= qt; ++j) {
        int kv0 = j * 64;
        __syncthreads();
        {   // transpose-stage V tile
            const u16* p0 = vbase + (size_t)(kv0 + 2*sp) * DKV_ + sg*8;
            uint4 r0 = *(const uint4*)p0;
            uint4 r1 = *(const uint4*)(p0 + DKV_);
            const u16* a0 = (const u16*)&r0;
            const u16* a1 = (const u16*)&r1;
            int kvs = (2*sp) ^ (8*sg);
            #pragma unroll
            for (int jx = 0; jx < 8; ++jx) {
                unsigned pk = (unsigned)a0[jx] | ((unsigned)a1[jx] << 16);
                *(unsigned*)(&Vt[(sg*8 + jx)*64 + kvs]) = pk;
            }
        }
        __syncthreads();

        // S = Q K^T
        f32x4 sacc[4] = {};
        #pragma unroll
        for (int nt = 0; nt < 4; ++nt) {
            const u16* kp = k + ((size_t)(b*S_ + kv0 + nt*16 + lr) * DKV_ + kvh*HD_ + quad*8);
            bf16x8 bk0 = *(const bf16x8*)(kp);
            bf16x8 bk1 = *(const bf16x8*)(kp + 32);
            sacc[nt] = __builtin_amdgcn_mfma_f32_16x16x32_bf16(aq[0], bk0, sacc[nt], 0, 0, 0);
            sacc[nt] = __builtin_amdgcn_mfma_f32_16x16x32_bf16(aq[1], bk1, sacc[nt], 0, 0, 0);
        }

        // P = exp2(S*SC - 4)  (fixed offset; masked on diagonal tile only)
        u16* pw = &Ps[wv*16*LP];
        if (j == qt) {
            #pragma unroll
            for (int nt = 0; nt < 4; ++nt) {
                int kg = kv0 + nt*16 + lr;
                #pragma unroll
                for (int r = 0; r < 4; ++r) {
                    int qg = qrow_base + quad*4 + r;
                    float p = exp2f(fmaf(sacc[nt][r], SC, -4.0f));
                    if (kg > qg) p = 0.f;
                    pw[(quad*4 + r)*LP + nt*16 + lr] = f2bf(p);
                }
            }
        } else {
            #pragma unroll
            for (int nt = 0; nt < 4; ++nt)
                #pragma unroll
                for (int r = 0; r < 4; ++r) {
                    float p = exp2f(fmaf(sacc[nt][r], SC, -4.0f));
                    pw[(quad*4 + r)*LP + nt*16 + lr] = f2bf(p);
                }
        }
        bf16x8 ap0 = *(const bf16x8*)(&pw[lr*LP + quad*8]);
        bf16x8 ap1 = *(const bf16x8*)(&pw[lr*LP + 32 + quad*8]);

        // O += P V ; l += P 1
        #pragma unroll
        for (int nt = 0; nt < 4; ++nt) {
            int d = nt*16 + lr;
            int sw = 8*((d>>3)&7);
            bf16x8 bv0 = *(const bf16x8*)(&Vt[d*64 + ((quad*8) ^ sw)]);
            bf16x8 bv1 = *(const bf16x8*)(&Vt[d*64 + ((32 + quad*8) ^ sw)]);
            oacc[nt] = __builtin_amdgcn_mfma_f32_16x16x32_bf16(ap0, bv0, oacc[nt], 0, 0, 0);
            oacc[nt] = __builtin_amdgcn_mfma_f32_16x16x32_bf16(ap1, bv1, oacc[nt], 0, 0, 0);
        }
        lacc = __builtin_amdgcn_mfma_f32_16x16x32_bf16(ap0, ones, lacc, 0, 0, 0);
        lacc = __builtin_amdgcn_mfma_f32_16x16x32_bf16(ap1, ones, lacc, 0, 0, 0);
    }

    #pragma unroll
    for (int nt = 0; nt < 4; ++nt)
        #pragma unroll
        for (int r = 0; r < 4; ++r) {
            int srow = qrow_base + quad*4 + r;
            z[(size_t)(b*S_ + srow) * D_ + h*HD_ + nt*16 + lr] = f2bf(oacc[nt][r] / lacc[r]);
        }
}

extern "C" void kernel_launch(void* const* d_in, const int* in_sizes, int n_in,
                              void* d_out, int out_size, void* d_ws, size_t ws_size,
                              hipStream_t stream) {
    const float* x  = (const float*)d_in[0];
    const float* Wq = (const float*)d_in[1];
    const float* Wk = (const float*)d_in[2];
    const float* Wv = (const float*)d_in[3];
    const float* Wo = (const float*)d_in[4];
    float* out = (float*)d_out;
    char* ws = (char*)d_ws;

    const size_t SZ_TAB = 524288;
    const size_t SZ_XB  = (size_t)M_*D_*2;      // 16.78M
    const size_t SZ_WQ  = (size_t)D_*D_*2;      // 8.39M
    const size_t SZ_WK  = (size_t)DKV_*D_*2;    // 2.10M
    const size_t SZ_Q   = (size_t)M_*D_*2;
    const size_t SZ_K   = (size_t)M_*DKV_*2;
    size_t need_fast = SZ_TAB + SZ_XB + SZ_WQ + 2*SZ_WK + SZ_Q + 2*SZ_K;  // 55,050,240

    float* tab = (float*)ws;

    if (ws_size >= need_fast) {
        // fast path: pre-convert everything to bf16, m97-style GEMMs
        u16* xb  = (u16*)(ws + SZ_TAB);
        u16* Wqb = (u16*)(ws + SZ_TAB + SZ_XB);              // reused for Wo after Q-gemm
        u16* Wkb = (u16*)(ws + SZ_TAB + SZ_XB + SZ_WQ);
        u16* Wvb = (u16*)(ws + SZ_TAB + SZ_XB + SZ_WQ + SZ_WK);
        u16* qbuf = (u16*)(ws + SZ_TAB + SZ_XB + SZ_WQ + 2*SZ_WK);
        u16* kbuf = (u16*)((char*)qbuf + SZ_Q);
        u16* vbuf = (u16*)((char*)kbuf + SZ_K);
        u16* zbuf = xb;   // x no longer needed once QKV gemms done

        rope_table_kernel<<<256, 256, 0, stream>>>(tab);
        cvt_bf16_kernel<<<(M_*D_/8 + 255)/256,   256, 0, stream>>>(x,  xb,  M_*D_/8);
        cvt_bf16_kernel<<<(D_*D_/8 + 255)/256,   256, 0, stream>>>(Wq, Wqb, D_*D_/8);
        cvt_bf16_kernel<<<(DKV_*D_/8 + 255)/256, 256, 0, stream>>>(Wk, Wkb, DKV_*D_/8);
        cvt_bf16_kernel<<<(DKV_*D_/8 + 255)/256, 256, 0, stream>>>(Wv, Wvb, DKV_*D_/8);

        gemm_bt_bf16<false><<<dim3(D_/128,   M_/128), 256, 0, stream>>>(xb, Wqb, qbuf, D_,   D_);
        gemm_bt_bf16<false><<<dim3(DKV_/128, M_/128), 256, 0, stream>>>(xb, Wkb, kbuf, DKV_, D_);
        gemm_bt_bf16<false><<<dim3(DKV_/128, M_/128), 256, 0, stream>>>(xb, Wvb, vbuf, DKV_, D_);
        cvt_bf16_kernel<<<(D_*D_/8 + 255)/256,   256, 0, stream>>>(Wo, Wqb, D_*D_/8);  // after Q-gemm

        rope_apply_kernel<<<(M_*H_*32)/256,   256, 0, stream>>>(qbuf, tab, H_);
        rope_apply_kernel<<<(M_*HKV_*32)/256, 256, 0, stream>>>(kbuf, tab, HKV_);
        attn_kernel<<<dim3(S_/64, H_, B_), 256, 0, stream>>>(qbuf, kbuf, vbuf, zbuf);
        gemm_bt_bf16<true><<<dim3(D_/128, M_/128), 256, 0, stream>>>(zbuf, Wqb, out, D_, D_);
    } else {
        // fallback (round-2 footprint, 42.5MB): convert-in-staging GEMMs
        u16* qbuf = (u16*)(ws + SZ_TAB);
        u16* kbuf = (u16*)((char*)qbuf + SZ_Q);
        u16* vbuf = (u16*)((char*)kbuf + SZ_K);
        u16* zbuf = (u16*)((char*)vbuf + SZ_K);

        rope_table_kernel<<<256, 256, 0, stream>>>(tab);
        gemm_bt<true, true, false><<<dim3(D_/128,   M_/128), 256, 0, stream>>>(x, Wq, qbuf, M_, D_,   D_);
        gemm_bt<true, true, false><<<dim3(DKV_/128, M_/128), 256, 0, stream>>>(x, Wk, kbuf, M_, DKV_, D_);
        gemm_bt<true, true, false><<<dim3(DKV_/128, M_/128), 256, 0, stream>>>(x, Wv, vbuf, M_, DKV_, D_);
        rope_apply_kernel<<<(M_*H_*32)/256,   256, 0, stream>>>(qbuf, tab, H_);
        rope_apply_kernel<<<(M_*HKV_*32)/256, 256, 0, stream>>>(kbuf, tab, HKV_);
        attn_kernel<<<dim3(S_/64, H_, B_), 256, 0, stream>>>(qbuf, kbuf, vbuf, zbuf);
        gemm_bt<false, true, true><<<dim3(D_/128, M_/128), 256, 0, stream>>>(zbuf, Wo, out, M_, D_, D_);
    }
}

// Round 4
// 411.373 us; speedup vs baseline: 2.4590x; 1.3698x over previous
//
#include <hip/hip_runtime.h>
#include <hip/hip_bf16.h>
#include <math.h>

#define B_   2
#define S_   2048
#define H_   32
#define HKV_ 8
#define HD_  64
#define D_   2048
#define DKV_ 512
#define M_   (B_*S_)

typedef __attribute__((ext_vector_type(8))) short bf16x8;
typedef __attribute__((ext_vector_type(4))) float f32x4;
typedef unsigned short u16;

__device__ __forceinline__ u16 f2bf(float f) {
    union { float f; unsigned u; } v; v.f = f;
    unsigned r = v.u + 0x7fff + ((v.u >> 16) & 1);
    return (u16)(r >> 16);
}

// async global->LDS, 16B per lane; LDS dest = uniform base + lane*16
typedef __attribute__((address_space(3))) void lds_void;
typedef const __attribute__((address_space(1))) void g_void;
__device__ __forceinline__ void gl_lds16(const void* g, void* l) {
    __builtin_amdgcn_global_load_lds((g_void*)g, (lds_void*)l, 16, 0, 0);
}

// ---------------- RoPE table: cos/sin(s * 2*pi * theta^(-i/32)) ----------------
__global__ void rope_table_kernel(float* __restrict__ tab) {
    int idx = blockIdx.x * blockDim.x + threadIdx.x;   // 65536 entries
    int s = idx >> 5, i = idx & 31;
    double freq = pow(10000.0, -(double)i / 32.0);
    double ang = (double)s * 6.283185307179586476925286766559 * freq;
    tab[2*idx]   = (float)cos(ang);
    tab[2*idx+1] = (float)sin(ang);
}

// ---------------- fused f32->bf16 conversion: x, Wq, Wk, Wv ----------------
// 8-elem units: x 1048576 | Wq 524288 | Wk 131072 | Wv 131072  (total 1835008)
__global__ void cvt_all_kernel(const float* __restrict__ x,  const float* __restrict__ wq,
                               const float* __restrict__ wk, const float* __restrict__ wv,
                               u16* __restrict__ xb, u16* __restrict__ wall) {
    int i = blockIdx.x * blockDim.x + threadIdx.x;
    if (i >= 1835008) return;
    const float* src; u16* dst;
    size_t e = (size_t)i * 8;
    if (i < 1048576)      { src = x  + e;            dst = xb + e; }
    else if (i < 1572864) { src = wq + (e - 8388608);  dst = wall + (e - 8388608); }
    else if (i < 1703936) { src = wk + (e - 12582912); dst = wall + 4194304 + (e - 12582912); }
    else                  { src = wv + (e - 13631488); dst = wall + 5242880 + (e - 13631488); }
    float4 a = *(const float4*)src;
    float4 b = *(const float4*)(src + 4);
    u16 tmp[8] = {f2bf(a.x), f2bf(a.y), f2bf(a.z), f2bf(a.w),
                  f2bf(b.x), f2bf(b.y), f2bf(b.z), f2bf(b.w)};
    *(uint4*)dst = *(const uint4*)tmp;
}

__global__ void cvt_bf16_kernel(const float* __restrict__ src, u16* __restrict__ dst, int n8) {
    int i = blockIdx.x * blockDim.x + threadIdx.x;
    if (i >= n8) return;
    const float4* p = (const float4*)(src + (size_t)i * 8);
    float4 a = p[0], b = p[1];
    u16 tmp[8] = {f2bf(a.x), f2bf(a.y), f2bf(a.z), f2bf(a.w),
                  f2bf(b.x), f2bf(b.y), f2bf(b.z), f2bf(b.w)};
    *(uint4*)(dst + (size_t)i * 8) = *(const uint4*)tmp;
}

// ============ fast GEMM (m97): Y[M,N] = X[M,K] @ W[N,K]^T, bf16 in; optional RoPE epi ============
template<bool YF32, bool ROPE>
__launch_bounds__(256, 2)
__global__ void gemm_bt_bf16(const u16* __restrict__ X, const u16* __restrict__ W,
                             void* __restrict__ Y, const float2* __restrict__ tab,
                             int Ndim, int Kdim) {
    __shared__ u16 As[128*32];
    __shared__ u16 Bs[128*32];
    int tid = threadIdx.x;
    int wv = tid >> 6, lane = tid & 63;
    int quad = lane >> 4, lr = lane & 15;
    int wm = wv >> 1, wn = wv & 1;
    int m0 = blockIdx.y * 128, n0 = blockIdx.x * 128;

    int srow = wv*32 + (lane >> 2);
    int scol = (lane & 3) * 8;
    const u16* xp = X + (size_t)(m0 + srow)*Kdim + scol;
    const u16* wp = W + (size_t)(n0 + srow)*Kdim + scol;

    f32x4 acc[4][4] = {};
    for (int k0 = 0; k0 < Kdim; k0 += 32) {
        __syncthreads();
        gl_lds16(xp + k0,                   &As[wv*1024]);
        gl_lds16(xp + 16*(size_t)Kdim + k0, &As[wv*1024 + 512]);
        gl_lds16(wp + k0,                   &Bs[wv*1024]);
        gl_lds16(wp + 16*(size_t)Kdim + k0, &Bs[wv*1024 + 512]);
        __syncthreads();
        bf16x8 af[4], bfr[4];
        #pragma unroll
        for (int t = 0; t < 4; ++t) {
            af[t]  = *(const bf16x8*)(&As[(wm*64 + t*16 + lr)*32 + quad*8]);
            bfr[t] = *(const bf16x8*)(&Bs[(wn*64 + t*16 + lr)*32 + quad*8]);
        }
        #pragma unroll
        for (int mt = 0; mt < 4; ++mt)
            #pragma unroll
            for (int nt = 0; nt < 4; ++nt)
                acc[mt][nt] = __builtin_amdgcn_mfma_f32_16x16x32_bf16(af[mt], bfr[nt], acc[mt][nt], 0, 0, 0);
    }
    #pragma unroll
    for (int mt = 0; mt < 4; ++mt)
        #pragma unroll
        for (int nt = 0; nt < 4; ++nt)
            #pragma unroll
            for (int r = 0; r < 4; ++r) {
                int m = m0 + wm*64 + mt*16 + quad*4 + r;
                int n = n0 + wn*64 + nt*16 + lr;
                float val = acc[mt][nt][r];
                if constexpr (ROPE) {
                    float partner = __shfl_xor(val, 1);
                    if (n < 2560) {  // block-uniform (n0 multiple of 128)
                        float2 cs = tab[(size_t)(m & (S_-1))*32 + ((n >> 1) & 31)];
                        val = fmaf(cs.x, val, ((n & 1) ? cs.y : -cs.y) * partner);
                    }
                }
                if constexpr (YF32)
                    ((float*)Y)[(size_t)m*Ndim + n] = val;
                else
                    ((u16*)Y)[(size_t)m*Ndim + n] = f2bf(val);
            }
}

// ============ fallback GEMM: f32 inputs converted during staging ============
#define LDK 40
template<bool F32>
__device__ __forceinline__ void stage8(const void* src, u16* dst, size_t row, int col, int ld) {
    if constexpr (F32) {
        const float* p = (const float*)src + row * (size_t)ld + col;
        float4 a = *(const float4*)p;
        float4 b = *(const float4*)(p + 4);
        u16 tmp[8] = {f2bf(a.x), f2bf(a.y), f2bf(a.z), f2bf(a.w),
                      f2bf(b.x), f2bf(b.y), f2bf(b.z), f2bf(b.w)};
        *(uint4*)dst = *(const uint4*)tmp;
    } else {
        const u16* p = (const u16*)src + row * (size_t)ld + col;
        *(uint4*)dst = *(const uint4*)p;
    }
}

template<bool XF32, bool WF32, bool YF32, bool ROPE>
__launch_bounds__(256, 2)
__global__ void gemm_bt(const void* __restrict__ X, const void* __restrict__ W,
                        void* __restrict__ Y, const float2* __restrict__ tab,
                        int Ndim, int Kdim) {
    __shared__ u16 As[128*LDK];
    __shared__ u16 Bs[128*LDK];
    int tid = threadIdx.x;
    int wv = tid >> 6, lane = tid & 63;
    int quad = lane >> 4, lr = lane & 15;
    int wm = wv >> 1, wn = wv & 1;
    int m0 = blockIdx.y * 128, n0 = blockIdx.x * 128;

    f32x4 acc[4][4] = {};
    for (int k0 = 0; k0 < Kdim; k0 += 32) {
        __syncthreads();
        #pragma unroll
        for (int it = 0; it < 2; ++it) {
            int e = (it*256 + tid) * 8;
            int r = e >> 5, kk = e & 31;
            stage8<XF32>(X, &As[r*LDK + kk], (size_t)(m0 + r), k0 + kk, Kdim);
            stage8<WF32>(W, &Bs[r*LDK + kk], (size_t)(n0 + r), k0 + kk, Kdim);
        }
        __syncthreads();
        bf16x8 af[4], bfr[4];
        #pragma unroll
        for (int t = 0; t < 4; ++t) {
            af[t]  = *(const bf16x8*)(&As[(wm*64 + t*16 + lr)*LDK + quad*8]);
            bfr[t] = *(const bf16x8*)(&Bs[(wn*64 + t*16 + lr)*LDK + quad*8]);
        }
        #pragma unroll
        for (int mt = 0; mt < 4; ++mt)
            #pragma unroll
            for (int nt = 0; nt < 4; ++nt)
                acc[mt][nt] = __builtin_amdgcn_mfma_f32_16x16x32_bf16(af[mt], bfr[nt], acc[mt][nt], 0, 0, 0);
    }
    #pragma unroll
    for (int mt = 0; mt < 4; ++mt)
        #pragma unroll
        for (int nt = 0; nt < 4; ++nt)
            #pragma unroll
            for (int r = 0; r < 4; ++r) {
                int m = m0 + wm*64 + mt*16 + quad*4 + r;
                int n = n0 + wn*64 + nt*16 + lr;
                float val = acc[mt][nt][r];
                if constexpr (ROPE) {
                    float partner = __shfl_xor(val, 1);
                    if (n < 2560) {
                        float2 cs = tab[(size_t)(m & (S_-1))*32 + ((n >> 1) & 31)];
                        val = fmaf(cs.x, val, ((n & 1) ? cs.y : -cs.y) * partner);
                    }
                }
                if constexpr (YF32)
                    ((float*)Y)[(size_t)m*Ndim + n] = val;
                else
                    ((u16*)Y)[(size_t)m*Ndim + n] = f2bf(val);
            }
}

// ---------------- Flash attention v3 ----------------
// Q-tile 128 (wave w: rows w*32..w*32+32, 2 m-frags). KV-tile 64.
// qkv packed layout, row stride 3072: Q at col h*64, K at 2048+kvh*64, V at 2560+kvh*64.
// Single barrier/iter; Ks double-buffered via global_load_lds (16B-block swizzle:
// chunk dc of row kv stored at slot dc^(kv&7)); Vt double-buffered, transposed with
// u16 swizzle kv^8*((d&7)^((d>>3)&7)); Ps per-wave 32x64, swizzle col^8*(row&7).
// All fragment b128 reads hit all 8 bank-groups uniformly (8 lanes each).
__launch_bounds__(256, 3)
__global__ void attn_kernel(const u16* __restrict__ qkv, u16* __restrict__ z) {
    __shared__ u16 Ks[2][64*64];
    __shared__ u16 Vt[2][64*64];
    __shared__ u16 Ps[4][32*64];
    int tid = threadIdx.x;
    int wv = tid >> 6, lane = tid & 63;
    int quad = lane >> 4, lr = lane & 15;
    int b = blockIdx.z, h = blockIdx.y;
    int qt = ((int)gridDim.x - 1) - (int)blockIdx.x;   // long blocks first
    int kvh = h >> 2;
    int qrow_base = qt*128 + wv*32;
    int jmax = 2*qt + 1;

    const u16* qkvb = qkv + (size_t)(b*S_) * 3072;
    const u16* kbase = qkvb + 2048 + kvh*64;

    int kr = lane >> 3;       // K-stage row-in-call
    int dcs = lane & 7;       // K-stage chunk slot
    int sg = tid & 7;         // V-stage d-chunk
    int sp = tid >> 3;        // V-stage kv-pair (0..31)
    const u16* vbase = qkvb + 2560 + kvh*64 + sg*8;

    // prime j=0: K(0) glds + V(0) regs (drained at first barrier)
    #pragma unroll
    for (int i = 0; i < 2; ++i) {
        int c = 2*wv + i;
        int kvloc = c*8 + kr;
        int dc = dcs ^ (kvloc & 7);
        gl_lds16(kbase + (size_t)kvloc*3072 + dc*8, &Ks[0][c*512]);
    }
    uint4 vr0 = *(const uint4*)(vbase + (size_t)(2*sp)*3072);
    uint4 vr1 = *(const uint4*)(vbase + (size_t)(2*sp + 1)*3072);

    // Q fragments
    bf16x8 aq[2][2];
    #pragma unroll
    for (int mt = 0; mt < 2; ++mt) {
        const u16* qp = qkvb + (size_t)(qrow_base + mt*16 + lr)*3072 + h*64 + quad*8;
        aq[mt][0] = *(const bf16x8*)(qp);
        aq[mt][1] = *(const bf16x8*)(qp + 32);
    }
    bf16x8 ones;
    #pragma unroll
    for (int i = 0; i < 8; ++i) ones[i] = (short)0x3F80;

    f32x4 oacc[2][4] = {};
    f32x4 lacc[2] = {};
    const float SC = 0.18033688f;   // 0.125 * log2(e)

    for (int j = 0; j <= jmax; ++j) {
        int buf = j & 1;
        // write Vt(j) from prefetched regs
        {
            const u16* a0 = (const u16*)&vr0;
            const u16* a1 = (const u16*)&vr1;
            #pragma unroll
            for (int jx = 0; jx < 8; ++jx) {
                unsigned pk = (unsigned)a0[jx] | ((unsigned)a1[jx] << 16);
                int kvs = (2*sp) ^ (8*(jx ^ sg));
                *(unsigned*)(&Vt[buf][(sg*8 + jx)*64 + kvs]) = pk;
            }
        }
        __syncthreads();   // drains K(j) glds; publishes Vt(j)

        if (j < jmax) {    // prefetch K(j+1), V(j+1) — land during compute(j)
            int kvn = (j+1)*64;
            #pragma unroll
            for (int i = 0; i < 2; ++i) {
                int c = 2*wv + i;
                int kvloc = c*8 + kr;
                int dc = dcs ^ (kvloc & 7);
                gl_lds16(kbase + (size_t)(kvn + kvloc)*3072 + dc*8, &Ks[buf^1][c*512]);
            }
            vr0 = *(const uint4*)(vbase + (size_t)(kvn + 2*sp)*3072);
            vr1 = *(const uint4*)(vbase + (size_t)(kvn + 2*sp + 1)*3072);
        }

        int kv0 = j*64;
        if (kv0 < qrow_base + 32) {   // wave has unmasked rows
            // S = Q K^T
            f32x4 sacc[2][4] = {};
            #pragma unroll
            for (int nt = 0; nt < 4; ++nt) {
                int kv = nt*16 + lr;
                #pragma unroll
                for (int ks = 0; ks < 2; ++ks) {
                    bf16x8 bk = *(const bf16x8*)(&Ks[buf][kv*64 + (((ks*4 + quad) ^ (kv & 7))*8)]);
                    sacc[0][nt] = __builtin_amdgcn_mfma_f32_16x16x32_bf16(aq[0][ks], bk, sacc[0][nt], 0, 0, 0);
                    sacc[1][nt] = __builtin_amdgcn_mfma_f32_16x16x32_bf16(aq[1][ks], bk, sacc[1][nt], 0, 0, 0);
                }
            }
            // P = exp2(S*SC - 4), diagonal-masked only where needed
            u16* pw = Ps[wv];
            if (kv0 + 63 > qrow_base) {
                #pragma unroll
                for (int mt = 0; mt < 2; ++mt)
                    #pragma unroll
                    for (int nt = 0; nt < 4; ++nt) {
                        int kg = kv0 + nt*16 + lr;
                        #pragma unroll
                        for (int r = 0; r < 4; ++r) {
                            int row = mt*16 + quad*4 + r;
                            float p = exp2f(fmaf(sacc[mt][nt][r], SC, -4.0f));
                            if (kg > qrow_base + row) p = 0.f;
                            pw[row*64 + ((nt*16 + lr) ^ (8*(row & 7)))] = f2bf(p);
                        }
                    }
            } else {
                #pragma unroll
                for (int mt = 0; mt < 2; ++mt)
                    #pragma unroll
                    for (int nt = 0; nt < 4; ++nt)
                        #pragma unroll
                        for (int r = 0; r < 4; ++r) {
                            int row = mt*16 + quad*4 + r;
                            float p = exp2f(fmaf(sacc[mt][nt][r], SC, -4.0f));
                            pw[row*64 + ((nt*16 + lr) ^ (8*(row & 7)))] = f2bf(p);
                        }
            }
            // A-frags of P (same-wave LDS round trip)
            bf16x8 ap[2][2];
            #pragma unroll
            for (int mt = 0; mt < 2; ++mt) {
                int row = mt*16 + lr;
                ap[mt][0] = *(const bf16x8*)(&pw[row*64 + ((quad*8) ^ (8*(lr & 7)))]);
                ap[mt][1] = *(const bf16x8*)(&pw[row*64 + ((32 + quad*8) ^ (8*(lr & 7)))]);
            }
            // O += P V ; l += P 1
            #pragma unroll
            for (int nt = 0; nt < 4; ++nt) {
                int d = nt*16 + lr;
                int g8 = 8*((d & 7) ^ ((d >> 3) & 7));
                bf16x8 bv0 = *(const bf16x8*)(&Vt[buf][d*64 + ((quad*8) ^ g8)]);
                bf16x8 bv1 = *(const bf16x8*)(&Vt[buf][d*64 + ((32 + quad*8) ^ g8)]);
                #pragma unroll
                for (int mt = 0; mt < 2; ++mt) {
                    oacc[mt][nt] = __builtin_amdgcn_mfma_f32_16x16x32_bf16(ap[mt][0], bv0, oacc[mt][nt], 0, 0, 0);
                    oacc[mt][nt] = __builtin_amdgcn_mfma_f32_16x16x32_bf16(ap[mt][1], bv1, oacc[mt][nt], 0, 0, 0);
                }
            }
            #pragma unroll
            for (int mt = 0; mt < 2; ++mt) {
                lacc[mt] = __builtin_amdgcn_mfma_f32_16x16x32_bf16(ap[mt][0], ones, lacc[mt], 0, 0, 0);
                lacc[mt] = __builtin_amdgcn_mfma_f32_16x16x32_bf16(ap[mt][1], ones, lacc[mt], 0, 0, 0);
            }
        }
    }

    #pragma unroll
    for (int mt = 0; mt < 2; ++mt)
        #pragma unroll
        for (int nt = 0; nt < 4; ++nt)
            #pragma unroll
            for (int r = 0; r < 4; ++r) {
                int row = qrow_base + mt*16 + quad*4 + r;
                z[(size_t)(b*S_ + row)*D_ + h*64 + nt*16 + lr] = f2bf(oacc[mt][nt][r] / lacc[mt][r]);
            }
}

extern "C" void kernel_launch(void* const* d_in, const int* in_sizes, int n_in,
                              void* d_out, int out_size, void* d_ws, size_t ws_size,
                              hipStream_t stream) {
    const float* x  = (const float*)d_in[0];
    const float* Wq = (const float*)d_in[1];
    const float* Wk = (const float*)d_in[2];
    const float* Wv = (const float*)d_in[3];
    const float* Wo = (const float*)d_in[4];
    float* out = (float*)d_out;
    char* ws = (char*)d_ws;

    // fast-path layout (total 55,050,240 B — proven to fit in round 3)
    const size_t OFF_XB   = 0;               // 16,777,216  (xb; later zbuf@0 + Wob@16,777,216)
    const size_t OFF_WALL = 16777216;        // 12,582,912  ([Wq;Wk;Wv] rows, 3072x2048)
    const size_t OFF_TAB  = 29360128;        //    524,288
    const size_t OFF_QKV  = 29884416;        // 25,165,824  (4096x3072 bf16)
    const size_t NEED     = 55050240;

    float*  tab  = (float*)(ws + OFF_TAB);
    float2* tab2 = (float2*)(ws + OFF_TAB);

    if (ws_size >= NEED) {
        u16* xb   = (u16*)(ws + OFF_XB);
        u16* wall = (u16*)(ws + OFF_WALL);
        u16* qkv  = (u16*)(ws + OFF_QKV);
        u16* zbuf = (u16*)(ws + OFF_XB);          // reuses xb after gemm1
        u16* wob  = (u16*)(ws + 16777216);        // reuses wall region? no — wall still live at gemm1; wob written AFTER gemm1 into freed WALL? wall free after gemm1 too, but write into xb-adjacent: use WALL region (freed after gemm1)

        rope_table_kernel<<<256, 256, 0, stream>>>(tab);
        cvt_all_kernel<<<7168, 256, 0, stream>>>(x, Wq, Wk, Wv, xb, wall);
        gemm_bt_bf16<false, true><<<dim3(24, 32), 256, 0, stream>>>(xb, wall, qkv, tab2, 3072, 2048);
        // wall + xb free now; convert Wo into wall region, z goes to xb region
        cvt_bf16_kernel<<<2048, 256, 0, stream>>>(Wo, wob, D_*D_/8);
        attn_kernel<<<dim3(16, 32, 2), 256, 0, stream>>>(qkv, zbuf);
        gemm_bt_bf16<true, false><<<dim3(16, 32), 256, 0, stream>>>(zbuf, wob, out, tab2, 2048, 2048);
    } else {
        // fallback: 42.4 MB — packed qkv, f32-staging gemms, rope in epilogue
        u16* qkv  = (u16*)(ws + 524288);
        u16* zbuf = (u16*)(ws + 524288 + (size_t)M_*3072*2);

        rope_table_kernel<<<256, 256, 0, stream>>>(tab);
        gemm_bt<true, true, false, true ><<<dim3(16, 32), 256, 0, stream>>>(x, Wq, qkv,        tab2, 3072, 2048);
        gemm_bt<true, true, false, true ><<<dim3(4,  32), 256, 0, stream>>>(x, Wk, qkv + 2048, tab2, 3072, 2048);
        gemm_bt<true, true, false, false><<<dim3(4,  32), 256, 0, stream>>>(x, Wv, qkv + 2560, tab2, 3072, 2048);
        attn_kernel<<<dim3(16, 32, 2), 256, 0, stream>>>(qkv, zbuf);
        gemm_bt<false, true, true, false><<<dim3(16, 32), 256, 0, stream>>>(zbuf, Wo, out, tab2, 2048, 2048);
    }
}